// Round 9
// baseline (136.508 us; speedup 1.0000x reference)
//
#include <hip/hip_runtime.h>
#include <hip/hip_bf16.h>

#define NEXP 16
#define KDIM 1024
#define ODIM 4096
#define NTOK 2048

#define BM   256                    // token rows per block (covers n_e)
#define BN   128                    // output cols per block (4 col-groups x 32)
#define KC   32                     // K per phase
#define NPH  (KDIM / KC)            // 32 phases
#define NBLK (NEXP * (ODIM / BN))   // 512 blocks = 2 per CU

typedef __attribute__((ext_vector_type(8))) short short8;
typedef __attribute__((ext_vector_type(4))) float f32x4;

typedef __attribute__((address_space(3))) unsigned lds_uint;
typedef const __attribute__((address_space(1))) unsigned glob_uint;

__device__ __forceinline__ void gload16(const void* g, void* l) {
    __builtin_amdgcn_global_load_lds((glob_uint*)g, (lds_uint*)l, 16, 0, 0);
}

__device__ __forceinline__ unsigned short f2bf(float f) {
    __hip_bfloat16 h = __float2bfloat16(f);
    return __builtin_bit_cast(unsigned short, h);
}

__device__ __forceinline__ short8 pack8(float4 a, float4 b) {
    short8 r;
    r[0] = (short)f2bf(a.x); r[1] = (short)f2bf(a.y);
    r[2] = (short)f2bf(a.z); r[3] = (short)f2bf(a.w);
    r[4] = (short)f2bf(b.x); r[5] = (short)f2bf(b.y);
    r[6] = (short)f2bf(b.z); r[7] = (short)f2bf(b.w);
    return r;
}

#define SFENCE() __builtin_amdgcn_sched_barrier(0)
#define WAITVM(N) do { SFENCE(); \
        asm volatile("s_waitcnt vmcnt(" #N ")" ::: "memory"); SFENCE(); } while (0)
#define WAITLG() do { SFENCE(); \
        asm volatile("s_waitcnt lgkmcnt(0)" ::: "memory"); SFENCE(); } while (0)

// ---------------------------------------------------------------------------
// Kernel 1: deterministic counting sort of tokens by expert (unchanged).
// ---------------------------------------------------------------------------
__global__ __launch_bounds__(256) void moe_sort(const int* __restrict__ gate,
                                                int* __restrict__ perm,
                                                int* __restrict__ offs) {
    __shared__ int lgate[NTOK];
    __shared__ int hist[256][NEXP + 1];
    __shared__ int base[NEXP];
    const int t = threadIdx.x;
    for (int i = t; i < NTOK; i += 256) lgate[i] = gate[i];
    #pragma unroll
    for (int e = 0; e < NEXP; ++e) hist[t][e] = 0;
    __syncthreads();
    const int TPT = NTOK / 256;
    for (int j = 0; j < TPT; ++j) hist[t][lgate[t * TPT + j]]++;
    __syncthreads();
    if (t < NEXP) {
        int s = 0;
        for (int i = 0; i < 256; ++i) { int v = hist[i][t]; hist[i][t] = s; s += v; }
        base[t] = s;
    }
    __syncthreads();
    if (t == 0) {
        int s = 0;
        for (int e = 0; e < NEXP; ++e) { int v = base[e]; base[e] = s; offs[e] = s; s += v; }
        offs[NEXP] = s;
    }
    __syncthreads();
    #pragma unroll
    for (int e = 0; e < NEXP; ++e) hist[t][e] += base[e];
    for (int j = 0; j < TPT; ++j) {
        int tok = t * TPT + j;
        int e = lgate[tok];
        int pos = hist[t][e]++;
        perm[pos] = tok;
    }
}

// ---------------------------------------------------------------------------
// Kernel 1.5: gather+convert A to bf16, oct-major A2T2[oct][pos][8 bf16].
// This layout makes the GEMM's A-fragment a DIRECT coalesced global read:
// for a fragment (fks, rows m*16..m*16+15) the 64 lanes cover 4 contiguous
// 256B segments. A2T2 is 4 MB -> L2-resident per XCD slice.
// ---------------------------------------------------------------------------
__global__ __launch_bounds__(256) void moe_cvt(const float* __restrict__ inp,
                                               const int* __restrict__ perm,
                                               unsigned short* __restrict__ A2T2) {
    const int o   = blockIdx.x;                 // 0..127 k-octet
    const int pos = blockIdx.y * 256 + threadIdx.x;
    const int tok = perm[pos];
    const float4* s = (const float4*)(inp + (size_t)tok * KDIM + o * 8);
    float4 v0 = s[0], v1 = s[1];
    *(short8*)(A2T2 + ((size_t)o * NTOK + pos) * 8) = pack8(v0, v1);
}

// ---------------------------------------------------------------------------
// Kernel 2: grouped GEMM. W through LDS (counted-vmcnt dbuf, read once
// chip-wide); A fragments DIRECT from global A2T2 (L2-resident, coalesced)
// -- no A staging, no A LDS, so the L2 A-stream runs in parallel with the
// HBM W-stream instead of sharing its staged path. LDS = 32 KB/block (B
// dbuf only), 2 blocks/CU. Per phase: STEP (af global loads + B frags from
// LDS + MFMA) -> read-barrier -> ISSUE_B(p+2) into freed buffer ->
// WAITVM(2) (p+1 landed, p+2's 2 loads in flight across barrier) -> barrier.
// ---------------------------------------------------------------------------
template <bool PRE>
__global__ __launch_bounds__(512, 4) void moe_gemm(
    const float* __restrict__ inp,
    const unsigned short* __restrict__ A2T2,
    const float* __restrict__ weight,
    const int* __restrict__ perm,
    const int* __restrict__ offs,
    float* __restrict__ out)
{
    const int bid = blockIdx.x;
    const int v   = (bid & 7) * (NBLK / 8) + (bid >> 3); // 64 consec/XCD = 2 experts
    const int e   = v >> 5;                              // 32 oc-tiles per expert
    const int oc  = (v & 31) * BN;

    const int beg = offs[e], end = offs[e + 1];
    const int nall = end - beg;
    if (nall <= 0) return;

    __shared__ float Bs[2][BN][KC];        // 32 KB fp32 (granule-swizzled)

    const int t    = threadIdx.x;          // 0..511
    const int lane = t & 63;
    const int w    = t >> 6;               // 0..7
    const int wm   = w >> 2;               // row half (128 rows)
    const int wn   = w & 3;                // col group (32 cols)
    const int frow = lane & 15;
    const int fks  = lane >> 4;            // 0..3 = k-octet within KC

    // ---- B staging: granule s in {t, t+512}; row=s>>3, slot=s&7.
    //      source granule = slot ^ (row&7)  (rule 21: swizzle the SOURCE) ----
    const int brow = t >> 3;               // 0..63
    const int hs   = (t & 7) ^ ((t >> 3) & 7);
    const float* bsrc0 = weight + ((size_t)e * ODIM + oc + brow) * KDIM + hs * 4;
    const float* bsrc1 = bsrc0 + (size_t)64 * KDIM;

#define ISSUE_B(buf, kc) {                                                    \
        gload16(bsrc0 + (kc), (char*)&Bs[buf][0][0] + t * 16);                \
        gload16(bsrc1 + (kc), (char*)&Bs[buf][0][0] + 8192 + t * 16);         \
    }

    for (int base = 0; base < nall; base += BM) {
        const int rows = (nall - base < BM) ? (nall - base) : BM;
        const int c0   = beg + base;
        const int mmax = rows - wm * 128;  // wave-uniform active m extent

        // ---- A-fragment sources ----
        // PRE: direct bf16 reads; padding rows read in-workspace garbage
        // (never stored: epilogue is r<rows guarded). !PRE: per-m token ids
        // (clamped), fragments packed from fp32 inp on the fly.
        const unsigned short* abase = 0;
        int tok8[8];
        if (PRE) {
            abase = A2T2 + ((size_t)fks * NTOK + (c0 + wm * 128 + frow)) * 8;
        } else {
            #pragma unroll
            for (int m = 0; m < 8; ++m) {
                int r = wm * 128 + m * 16 + frow; if (r > rows - 1) r = rows - 1;
                tok8[m] = perm[c0 + r];
            }
        }

        f32x4 acc[8][2];
        #pragma unroll
        for (int m = 0; m < 8; ++m) {
            acc[m][0] = (f32x4){0.f, 0.f, 0.f, 0.f};
            acc[m][1] = (f32x4){0.f, 0.f, 0.f, 0.f};
        }

        // ---- chunk top: prior-chunk consumers done, prime B pipeline ----
        WAITLG();
        __builtin_amdgcn_s_barrier();
        ISSUE_B(0, 0);
        ISSUE_B(1, KC);
        WAITVM(2);                          // stage0 landed; stage1 in flight
        __builtin_amdgcn_s_barrier();

        for (int p = 0; p < NPH; ++p) {
            const int cur = p & 1;
            // ---- STEP: B frags from LDS (cvt on idle VALU) + direct-A MFMA ----
            {
                int rB = wn * 32 + frow;
                const int x = rB & 7;
                float4 lo = *(const float4*)((const char*)&Bs[cur][0][0]
                             + rB * 128 + (((2 * fks)     ^ x) * 16));
                float4 hi = *(const float4*)((const char*)&Bs[cur][0][0]
                             + rB * 128 + (((2 * fks + 1) ^ x) * 16));
                short8 bfr0 = pack8(lo, hi);
                rB += 16;                   // (rB+16)&7 == x
                lo = *(const float4*)((const char*)&Bs[cur][0][0]
                             + rB * 128 + (((2 * fks)     ^ x) * 16));
                hi = *(const float4*)((const char*)&Bs[cur][0][0]
                             + rB * 128 + (((2 * fks + 1) ^ x) * 16));
                short8 bfr1 = pack8(lo, hi);
                #pragma unroll
                for (int m = 0; m < 8; ++m) {
                    if (m * 16 < mmax) {
                        short8 af;
                        if (PRE) {
                            af = *(const short8*)(abase + m * 128); // +m*16 rows
                        } else {
                            const float* fsrc = inp + (size_t)tok8[m] * KDIM
                                                + (p * 4 + fks) * 8;
                            af = pack8(*(const float4*)(fsrc),
                                       *(const float4*)(fsrc + 4));
                        }
                        acc[m][0] = __builtin_amdgcn_mfma_f32_16x16x32_bf16(af, bfr0, acc[m][0], 0, 0, 0);
                        acc[m][1] = __builtin_amdgcn_mfma_f32_16x16x32_bf16(af, bfr1, acc[m][1], 0, 0, 0);
                    }
                }
            }
            if (PRE) abase += (size_t)4 * NTOK * 8;   // next 4 k-octets

            WAITLG();
            __builtin_amdgcn_s_barrier();              // all reads of cur done
            if (p + 2 < NPH) {
                ISSUE_B(cur, (p + 2) * KC);            // refill freed buffer
                WAITVM(2);                 // p+1 landed; p+2's 2 stay in flight
            } else {
                WAITVM(0);                             // drain tail
            }
            if (p + 1 < NPH) __builtin_amdgcn_s_barrier();   // p+1 ready
        }

        // ---- epilogue: C layout col=lane&15, row=(lane>>4)*4+reg ----
        const int col0 = oc + wn * 32 + frow;
        #pragma unroll
        for (int m = 0; m < 8; ++m) {
            #pragma unroll
            for (int reg = 0; reg < 4; ++reg) {
                int r = wm * 128 + m * 16 + fks * 4 + reg;
                if (r < rows) {
                    int tok = perm[c0 + r];
                    float* orow = out + (size_t)tok * ODIM + col0;
                    orow[0]  = acc[m][0][reg];
                    orow[16] = acc[m][1][reg];
                }
            }
        }
    }
#undef ISSUE_B
}

extern "C" void kernel_launch(void* const* d_in, const int* in_sizes, int n_in,
                              void* d_out, int out_size, void* d_ws, size_t ws_size,
                              hipStream_t stream) {
    const float* inp    = (const float*)d_in[0];
    const int*   gate   = (const int*)d_in[1];
    const float* weight = (const float*)d_in[2];
    float*       out    = (float*)d_out;

    int* perm = (int*)d_ws;                          // 2048 ints
    int* offs = perm + NTOK;                         // 17 ints
    unsigned short* A2T2 = (unsigned short*)((char*)d_ws + 16384);
    // +64 KB slack so padded fragment over-reads stay in the workspace
    const size_t need = 16384 + (size_t)NTOK * KDIM * 2 + 65536;
    const bool pre = (ws_size >= need);              // host-side, deterministic

    moe_sort<<<1, 256, 0, stream>>>(gate, perm, offs);
    if (pre) {
        dim3 cg(KDIM / 8, NTOK / 256);               // 128 x 8
        moe_cvt<<<cg, 256, 0, stream>>>(inp, perm, A2T2);
        moe_gemm<true><<<NBLK, 512, 0, stream>>>(inp, A2T2, weight, perm, offs, out);
    } else {
        moe_gemm<false><<<NBLK, 512, 0, stream>>>(inp, A2T2, weight, perm, offs, out);
    }
}

// Round 11
// 122.718 us; speedup vs baseline: 1.1124x; 1.1124x over previous
//
#include <hip/hip_runtime.h>
#include <hip/hip_bf16.h>

#define NEXP 16
#define KDIM 1024
#define ODIM 4096
#define NTOK 2048

#define BM   256                    // token rows per block (covers n_e)
#define BN   128                    // output cols per block (4 col-groups x 32)
#define KC   32                     // K per phase
#define NPH  (KDIM / KC)            // 32 phases (even)
#define NBLK (NEXP * (ODIM / BN))   // 512 blocks = 2 per CU

typedef __attribute__((ext_vector_type(8))) short short8;
typedef __attribute__((ext_vector_type(4))) float f32x4;

typedef __attribute__((address_space(3))) unsigned lds_uint;
typedef const __attribute__((address_space(1))) unsigned glob_uint;

__device__ __forceinline__ void gload16(const void* g, void* l) {
    __builtin_amdgcn_global_load_lds((glob_uint*)g, (lds_uint*)l, 16, 0, 0);
}

__device__ __forceinline__ unsigned short f2bf(float f) {
    __hip_bfloat16 h = __float2bfloat16(f);
    return __builtin_bit_cast(unsigned short, h);
}

__device__ __forceinline__ short8 pack8(float4 a, float4 b) {
    short8 r;
    r[0] = (short)f2bf(a.x); r[1] = (short)f2bf(a.y);
    r[2] = (short)f2bf(a.z); r[3] = (short)f2bf(a.w);
    r[4] = (short)f2bf(b.x); r[5] = (short)f2bf(b.y);
    r[6] = (short)f2bf(b.z); r[7] = (short)f2bf(b.w);
    return r;
}

__device__ __forceinline__ short8 pack8v(f32x4 a, f32x4 b) {
    short8 r;
    r[0] = (short)f2bf(a[0]); r[1] = (short)f2bf(a[1]);
    r[2] = (short)f2bf(a[2]); r[3] = (short)f2bf(a[3]);
    r[4] = (short)f2bf(b[0]); r[5] = (short)f2bf(b[1]);
    r[6] = (short)f2bf(b[2]); r[7] = (short)f2bf(b[3]);
    return r;
}

#define SFENCE() __builtin_amdgcn_sched_barrier(0)
#define WAITLG() do { SFENCE(); \
        asm volatile("s_waitcnt lgkmcnt(0)" ::: "memory"); SFENCE(); } while (0)

// ---------------------------------------------------------------------------
// Kernel 1: deterministic counting sort of tokens by expert (unchanged).
// ---------------------------------------------------------------------------
__global__ __launch_bounds__(256) void moe_sort(const int* __restrict__ gate,
                                                int* __restrict__ perm,
                                                int* __restrict__ offs) {
    __shared__ int lgate[NTOK];
    __shared__ int hist[256][NEXP + 1];
    __shared__ int base[NEXP];
    const int t = threadIdx.x;
    for (int i = t; i < NTOK; i += 256) lgate[i] = gate[i];
    #pragma unroll
    for (int e = 0; e < NEXP; ++e) hist[t][e] = 0;
    __syncthreads();
    const int TPT = NTOK / 256;
    for (int j = 0; j < TPT; ++j) hist[t][lgate[t * TPT + j]]++;
    __syncthreads();
    if (t < NEXP) {
        int s = 0;
        for (int i = 0; i < 256; ++i) { int v = hist[i][t]; hist[i][t] = s; s += v; }
        base[t] = s;
    }
    __syncthreads();
    if (t == 0) {
        int s = 0;
        for (int e = 0; e < NEXP; ++e) { int v = base[e]; base[e] = s; offs[e] = s; s += v; }
        offs[NEXP] = s;
    }
    __syncthreads();
    #pragma unroll
    for (int e = 0; e < NEXP; ++e) hist[t][e] += base[e];
    for (int j = 0; j < TPT; ++j) {
        int tok = t * TPT + j;
        int e = lgate[tok];
        int pos = hist[t][e]++;
        perm[pos] = tok;
    }
}

// ---------------------------------------------------------------------------
// Kernel 1.5: gather+convert A to bf16, oct-major A2T2[oct][pos][8 bf16]
// (unchanged) -> GEMM A staging is a linear 16B-granule gload_lds copy.
// ---------------------------------------------------------------------------
__global__ __launch_bounds__(256) void moe_cvt(const float* __restrict__ inp,
                                               const int* __restrict__ perm,
                                               unsigned short* __restrict__ A2T2) {
    const int o   = blockIdx.x;                 // 0..127 k-octet
    const int pos = blockIdx.y * 256 + threadIdx.x;
    const int tok = perm[pos];
    const float4* s = (const float4*)(inp + (size_t)tok * KDIM + o * 8);
    float4 v0 = s[0], v1 = s[1];
    *(short8*)(A2T2 + ((size_t)o * NTOK + pos) * 8) = pack8(v0, v1);
}

// ---------------------------------------------------------------------------
// Kernel 2: grouped GEMM, depth-2 cover on BOTH streams.
// B (W, zero reuse): nontemporal f32x4 -> regs (Ra/Rb alternating) in phase
//   p for use at p+2; pack8v -> LDS at end of p+1. The compiler's counted
//   vmcnt before pack8v leaves p+2's loads in flight across the barrier; nt
//   keeps the 256MB W stream from evicting A panels out of L2.
// A (L2-resident A2T2): 3-stage gload_lds, issue p+2 during p. Its landing
//   before use is implied in-order by the pack8v wait (A issued before B).
// LDS 64KB/block (A 3x16 + B 2x8), 2 blocks/CU, 16 waves.
// Frag reads: oct-plane layouts, measured-conflict-free b128 pattern.
// ---------------------------------------------------------------------------
template <bool PRE>
__global__ __launch_bounds__(512, 4) void moe_gemm(
    const float* __restrict__ inp,
    const unsigned short* __restrict__ A2T2,
    const float* __restrict__ weight,
    const int* __restrict__ perm,
    const int* __restrict__ offs,
    float* __restrict__ out)
{
    const int bid = blockIdx.x;
    const int v   = (bid & 7) * (NBLK / 8) + (bid >> 3); // 64 consec/XCD = 2 experts
    const int e   = v >> 5;                              // 32 oc-tiles per expert
    const int oc  = (v & 31) * BN;

    const int beg = offs[e], end = offs[e + 1];
    const int nall = end - beg;
    if (nall <= 0) return;

    __shared__ short As[3][4][BM][8];      // 48 KB bf16 (oct-major, 3-stage)
    __shared__ short Bs[2][4][BN][8];      // 16 KB bf16 (oct-plane, dbuf)

    const int t    = threadIdx.x;          // 0..511
    const int lane = t & 63;
    const int w    = t >> 6;               // 0..7
    const int wm   = w >> 2;               // row half (128 rows)
    const int wn   = w & 3;                // col group (32 cols)
    const int frow = lane & 15;
    const int fks  = lane >> 4;            // 0..3 = k-octet within KC

    // B staging map: thread t = row (t>>2), k-octet (t&3); 4 consecutive
    // threads cover 128B of one W row -> coalesced.
    const float* bsrc = weight + ((size_t)e * ODIM + oc + (t >> 2)) * KDIM
                        + (t & 3) * 8;

#define LOADB(S, p) {                                                         \
        S##lo = __builtin_nontemporal_load((const f32x4*)(bsrc + (p) * KC));  \
        S##hi = __builtin_nontemporal_load((const f32x4*)(bsrc + (p) * KC + 4)); \
    }
#define CVTWB(S, buf) {                                                       \
        *(short8*)&Bs[buf][t & 3][t >> 2][0] = pack8v(S##lo, S##hi);          \
    }
#define ISSUE_A(st, p) {                                                      \
        gload16(asrc0 + (size_t)(p) * (4 * NTOK * 8),                         \
                (char*)&As[st][0][0][0] + t * 16);                            \
        gload16(asrc1 + (size_t)(p) * (4 * NTOK * 8),                         \
                (char*)&As[st][0][0][0] + 8192 + t * 16);                     \
    }
#define STEP(stA, bufB) {                                                     \
        const char* Ab = (const char*)&As[stA][0][0][0];                      \
        const char* Bb = (const char*)&Bs[bufB][0][0][0];                     \
        short8 bf0 = *(const short8*)(Bb + (fks * BN + wn * 32 + frow) * 16); \
        short8 bf1 = *(const short8*)(Bb + (fks * BN + wn * 32 + 16 + frow) * 16); \
        _Pragma("unroll")                                                     \
        for (int m = 0; m < 8; ++m) {                                         \
            if (m * 16 < mmax) {                                              \
                short8 af = *(const short8*)(Ab +                             \
                    (fks * BM + wm * 128 + m * 16 + frow) * 16);              \
                acc[m][0] = __builtin_amdgcn_mfma_f32_16x16x32_bf16(af, bf0, acc[m][0], 0, 0, 0); \
                acc[m][1] = __builtin_amdgcn_mfma_f32_16x16x32_bf16(af, bf1, acc[m][1], 0, 0, 0); \
            }                                                                 \
        }                                                                     \
    }

    for (int base = 0; base < nall; base += BM) {
        const int rows = (nall - base < BM) ? (nall - base) : BM;
        const int c0   = beg + base;
        const int mmax = rows - wm * 128;  // wave-uniform active m extent

        int rcl = t & 255; if (rcl > rows - 1) rcl = rows - 1;
        const unsigned short* asrc0 = A2T2 + ((size_t)(t >> 8) * NTOK + (c0 + rcl)) * 8;
        const unsigned short* asrc1 = A2T2 + ((size_t)((t >> 8) + 2) * NTOK + (c0 + rcl)) * 8;
        const float* afsrc = PRE ? 0
            : inp + (size_t)perm[c0 + rcl] * KDIM + (t >> 8) * 8;

        f32x4 acc[8][2];
        #pragma unroll
        for (int m = 0; m < 8; ++m) {
            acc[m][0] = (f32x4){0.f, 0.f, 0.f, 0.f};
            acc[m][1] = (f32x4){0.f, 0.f, 0.f, 0.f};
        }

        f32x4 Ralo, Rahi, Rblo, Rbhi;      // B staging reg sets (static names)

        if (PRE) {
            // ---- prologue: prior chunk consumers done, prime both streams ----
            WAITLG();
            __builtin_amdgcn_s_barrier();
            ISSUE_A(0, 0); LOADB(Ra, 0);
            ISSUE_A(1, 1); LOADB(Rb, 1);
            SFENCE();
            CVTWB(Ra, 0);                   // counted vmcnt: A0/B0 landed,
            WAITLG();                       //   A1/B1 stay in flight
            __builtin_amdgcn_s_barrier();

            int s0 = 0, s1 = 1, s2 = 2;
            for (int pp = 0; pp < NPH; pp += 2) {
                // even phase pp: reads As[s0], Bs[0]
                if (pp + 2 < NPH) { ISSUE_A(s2, pp + 2); LOADB(Ra, pp + 2); SFENCE(); }
                STEP(s0, 0);
                CVTWB(Rb, 1);               // B(pp+1); counted vmcnt leaves
                WAITLG();                   //   pp+2's loads in flight
                __builtin_amdgcn_s_barrier();
                // odd phase pp+1: reads As[s1], Bs[1]
                if (pp + 3 < NPH) { ISSUE_A(s0, pp + 3); LOADB(Rb, pp + 3); SFENCE(); }
                STEP(s1, 1);
                if (pp + 2 < NPH) {
                    CVTWB(Ra, 0);           // B(pp+2)
                    WAITLG();
                    __builtin_amdgcn_s_barrier();
                }
                int tmp = s2; s2 = s1; s1 = s0; s0 = tmp;   // (s0,s1,s2)<-(s2,s0,s1)
            }
        } else {
            // ---- fallback (unused when workspace suffices): simple 1-buf ----
            float4 Aa, Ab2, Ac, Ad;
            for (int p = 0; p < NPH; ++p) {
                Aa  = *(const float4*)(afsrc + p * KC);
                Ab2 = *(const float4*)(afsrc + p * KC + 4);
                Ac  = *(const float4*)(afsrc + p * KC + 16);
                Ad  = *(const float4*)(afsrc + p * KC + 20);
                LOADB(Ra, p);
                __syncthreads();            // readers of previous phase done
                *(short8*)((char*)&As[0][0][0][0] + t * 16)        = pack8(Aa, Ab2);
                *(short8*)((char*)&As[0][0][0][0] + 8192 + t * 16) = pack8(Ac, Ad);
                CVTWB(Ra, 0);
                __syncthreads();            // data visible
                STEP(0, 0);
            }
        }

        // ---- epilogue: C layout col=lane&15, row=(lane>>4)*4+reg ----
        const int col0 = oc + wn * 32 + frow;
        #pragma unroll
        for (int m = 0; m < 8; ++m) {
            #pragma unroll
            for (int reg = 0; reg < 4; ++reg) {
                int r = wm * 128 + m * 16 + fks * 4 + reg;
                if (r < rows) {
                    int tok = perm[c0 + r];
                    float* orow = out + (size_t)tok * ODIM + col0;
                    orow[0]  = acc[m][0][reg];
                    orow[16] = acc[m][1][reg];
                }
            }
        }
    }
#undef LOADB
#undef CVTWB
#undef ISSUE_A
#undef STEP
}

extern "C" void kernel_launch(void* const* d_in, const int* in_sizes, int n_in,
                              void* d_out, int out_size, void* d_ws, size_t ws_size,
                              hipStream_t stream) {
    const float* inp    = (const float*)d_in[0];
    const int*   gate   = (const int*)d_in[1];
    const float* weight = (const float*)d_in[2];
    float*       out    = (float*)d_out;

    int* perm = (int*)d_ws;                          // 2048 ints
    int* offs = perm + NTOK;                         // 17 ints
    unsigned short* A2T2 = (unsigned short*)((char*)d_ws + 16384);
    const size_t need = 16384 + (size_t)NTOK * KDIM * 2 + 65536;
    const bool pre = (ws_size >= need);              // host-side, deterministic

    moe_sort<<<1, 256, 0, stream>>>(gate, perm, offs);
    if (pre) {
        dim3 cg(KDIM / 8, NTOK / 256);               // 128 x 8
        moe_cvt<<<cg, 256, 0, stream>>>(inp, perm, A2T2);
        moe_gemm<true><<<NBLK, 512, 0, stream>>>(inp, A2T2, weight, perm, offs, out);
    } else {
        moe_gemm<false><<<NBLK, 512, 0, stream>>>(inp, A2T2, weight, perm, offs, out);
    }
}

// Round 12
// 95.715 us; speedup vs baseline: 1.4262x; 1.2821x over previous
//
#include <hip/hip_runtime.h>
#include <hip/hip_bf16.h>

#define NEXP 16
#define KDIM 1024
#define ODIM 4096
#define NTOK 2048

#define BM   256                    // token rows per block (covers n_e)
#define BN   256                    // output cols per block (8 col-groups x 32)
#define KC   32                     // K per phase
#define NPH  (KDIM / KC)            // 32 phases
#define NBLK (NEXP * (ODIM / BN))   // 256 blocks = 1 per CU

// LDS (bytes): W stage s at s*32768 ([256 row][8 slot][16B] fp32, slot holds
// source granule slot^(row&7)); A stage s at 98304+s*16384 ([4 oct][256 pos][16B] bf16).
#define WS(s) ((s) * 32768)
#define AS(s) (98304 + (s) * 16384)
#define LDS_BYTES (3 * 32768 + 3 * 16384)   // 144 KB

typedef __attribute__((ext_vector_type(8))) short short8;
typedef __attribute__((ext_vector_type(4))) float f32x4;

typedef __attribute__((address_space(3))) unsigned lds_uint;
typedef const __attribute__((address_space(1))) unsigned glob_uint;

__device__ __forceinline__ void gload16(const void* g, void* l) {
    __builtin_amdgcn_global_load_lds((glob_uint*)g, (lds_uint*)l, 16, 0, 0);
}

__device__ __forceinline__ unsigned short f2bf(float f) {
    __hip_bfloat16 h = __float2bfloat16(f);
    return __builtin_bit_cast(unsigned short, h);
}

__device__ __forceinline__ short8 pack8(float4 a, float4 b) {
    short8 r;
    r[0] = (short)f2bf(a.x); r[1] = (short)f2bf(a.y);
    r[2] = (short)f2bf(a.z); r[3] = (short)f2bf(a.w);
    r[4] = (short)f2bf(b.x); r[5] = (short)f2bf(b.y);
    r[6] = (short)f2bf(b.z); r[7] = (short)f2bf(b.w);
    return r;
}

__device__ __forceinline__ short8 pack8v(f32x4 a, f32x4 b) {
    short8 r;
    r[0] = (short)f2bf(a[0]); r[1] = (short)f2bf(a[1]);
    r[2] = (short)f2bf(a[2]); r[3] = (short)f2bf(a[3]);
    r[4] = (short)f2bf(b[0]); r[5] = (short)f2bf(b[1]);
    r[6] = (short)f2bf(b[2]); r[7] = (short)f2bf(b[3]);
    return r;
}

#define SFENCE() __builtin_amdgcn_sched_barrier(0)
#define WAITVM(N) do { SFENCE(); \
        asm volatile("s_waitcnt vmcnt(" #N ")" ::: "memory"); SFENCE(); } while (0)
#define BAR() do { SFENCE(); __builtin_amdgcn_s_barrier(); SFENCE(); } while (0)

// ---------------------------------------------------------------------------
// Kernel 1: deterministic counting sort of tokens by expert (unchanged).
// ---------------------------------------------------------------------------
__global__ __launch_bounds__(256) void moe_sort(const int* __restrict__ gate,
                                                int* __restrict__ perm,
                                                int* __restrict__ offs) {
    __shared__ int lgate[NTOK];
    __shared__ int hist[256][NEXP + 1];
    __shared__ int base[NEXP];
    const int t = threadIdx.x;
    for (int i = t; i < NTOK; i += 256) lgate[i] = gate[i];
    #pragma unroll
    for (int e = 0; e < NEXP; ++e) hist[t][e] = 0;
    __syncthreads();
    const int TPT = NTOK / 256;
    for (int j = 0; j < TPT; ++j) hist[t][lgate[t * TPT + j]]++;
    __syncthreads();
    if (t < NEXP) {
        int s = 0;
        for (int i = 0; i < 256; ++i) { int v = hist[i][t]; hist[i][t] = s; s += v; }
        base[t] = s;
    }
    __syncthreads();
    if (t == 0) {
        int s = 0;
        for (int e = 0; e < NEXP; ++e) { int v = base[e]; base[e] = s; offs[e] = s; s += v; }
        offs[NEXP] = s;
    }
    __syncthreads();
    #pragma unroll
    for (int e = 0; e < NEXP; ++e) hist[t][e] += base[e];
    for (int j = 0; j < TPT; ++j) {
        int tok = t * TPT + j;
        int e = lgate[tok];
        int pos = hist[t][e]++;
        perm[pos] = tok;
    }
}

// ---------------------------------------------------------------------------
// Kernel 1.5: gather+convert A to bf16, oct-major A2T2[oct][pos][8 bf16]
// (unchanged) -> GEMM A staging is a linear 16B-granule gload_lds copy.
// ---------------------------------------------------------------------------
__global__ __launch_bounds__(256) void moe_cvt(const float* __restrict__ inp,
                                               const int* __restrict__ perm,
                                               unsigned short* __restrict__ A2T2) {
    const int o   = blockIdx.x;                 // 0..127 k-octet
    const int pos = blockIdx.y * 256 + threadIdx.x;
    const int tok = perm[pos];
    const float4* s = (const float4*)(inp + (size_t)tok * KDIM + o * 8);
    float4 v0 = s[0], v1 = s[1];
    *(short8*)(A2T2 + ((size_t)o * NTOK + pos) * 8) = pack8(v0, v1);
}

// ---------------------------------------------------------------------------
// Kernel 2: byte-minimal grouped GEMM. 1024 threads (16 waves), 1 block/CU.
// Per-CU-phase staged bytes = 48 KB (W 32 KB fp32 + A 16 KB bf16) -- the
// minimum given irreducible fp32 W; chip logical ~355 MB. Zero ds_write,
// zero reg staging (both streams gload_lds, 3 stages, counted vmcnt(3):
// issue p+2 at phase-p start, wait p+1 landed, p+2 in flight across the
// single barrier per phase). W->bf16 cvt at fragment read on idle VALU.
// All LDS read/write geometries are the R8-measured-0-conflict patterns.
// ---------------------------------------------------------------------------
template <bool PRE>
__global__ __launch_bounds__(1024, 4) void moe_gemm(
    const float* __restrict__ inp,
    const unsigned short* __restrict__ A2T2,
    const float* __restrict__ weight,
    const int* __restrict__ perm,
    const int* __restrict__ offs,
    float* __restrict__ out)
{
    const int bid = blockIdx.x;
    const int v   = (bid & 7) * (NBLK / 8) + (bid >> 3); // 32 consec/XCD = 2 experts
    const int e   = v >> 4;                              // 16 oc-tiles per expert
    const int oc  = (v & 15) * BN;

    const int beg = offs[e], end = offs[e + 1];
    const int nall = end - beg;
    if (nall <= 0) return;

    __shared__ char lds[LDS_BYTES];

    const int t    = threadIdx.x;          // 0..1023
    const int lane = t & 63;
    const int w    = t >> 6;               // 0..15
    const int wm   = w >> 3;               // row half (128 rows)
    const int wn   = w & 7;                // col group (32 cols)
    const int frow = lane & 15;
    const int fks  = lane >> 4;            // 0..3 = k-octet within KC

    // ---- W staging: granule g in {t, t+1024}; row=g>>3, slot=g&7;
    //      source granule = slot ^ (row&7)  (rule 21: swizzle the SOURCE) ----
    const int wrow = t >> 3;               // 0..127
    const int hs   = (t & 7) ^ ((t >> 3) & 7);
    const float* bsrc0 = weight + ((size_t)e * ODIM + oc + wrow) * KDIM + hs * 4;
    const float* bsrc1 = bsrc0 + (size_t)128 * KDIM;

#define ISSUE_W(s, p) {                                                       \
        gload16(bsrc0 + (p) * KC, lds + WS(s) + t * 16);                      \
        gload16(bsrc1 + (p) * KC, lds + WS(s) + 16384 + t * 16);              \
    }
// A: granule t -> oct-plane t>>8, pos t&255 (linear dest).
#define ISSUE_A(s, p) {                                                       \
        gload16(asrcB + (size_t)(p) * (4 * NTOK * 8), lds + AS(s) + t * 16);  \
    }
#define STEP(s) {                                                             \
        const char* Wb = lds + WS(s);                                         \
        const char* Ab = lds + AS(s);                                         \
        int rB = wn * 32 + frow;                                              \
        const int x = frow & 7;                                               \
        f32x4 lo = *(const f32x4*)(Wb + (rB * 8 + ((2 * fks)     ^ x)) * 16); \
        f32x4 hi = *(const f32x4*)(Wb + (rB * 8 + ((2 * fks + 1) ^ x)) * 16); \
        short8 bf0 = pack8v(lo, hi);                                          \
        rB += 16;                                                             \
        lo = *(const f32x4*)(Wb + (rB * 8 + ((2 * fks)     ^ x)) * 16);       \
        hi = *(const f32x4*)(Wb + (rB * 8 + ((2 * fks + 1) ^ x)) * 16);       \
        short8 bf1 = pack8v(lo, hi);                                          \
        _Pragma("unroll")                                                     \
        for (int m = 0; m < 8; ++m) {                                         \
            if (m * 16 < mmax) {                                              \
                short8 af = *(const short8*)(Ab +                             \
                    (fks * 256 + wm * 128 + m * 16 + frow) * 16);             \
                acc[m][0] = __builtin_amdgcn_mfma_f32_16x16x32_bf16(af, bf0, acc[m][0], 0, 0, 0); \
                acc[m][1] = __builtin_amdgcn_mfma_f32_16x16x32_bf16(af, bf1, acc[m][1], 0, 0, 0); \
            }                                                                 \
        }                                                                     \
    }

    for (int base = 0; base < nall; base += BM) {
        const int rows = (nall - base < BM) ? (nall - base) : BM;
        const int c0   = beg + base;
        const int mmax = rows - wm * 128;  // wave-uniform active m extent

        int rcl = t & 255; if (rcl > rows - 1) rcl = rows - 1;
        const unsigned short* asrcB =
            A2T2 + ((size_t)(t >> 8) * NTOK + (c0 + rcl)) * 8;
        const float* afsrc = PRE ? 0
            : inp + (size_t)perm[c0 + rcl] * KDIM + (t >> 8) * 8;

        f32x4 acc[8][2];
        #pragma unroll
        for (int m = 0; m < 8; ++m) {
            acc[m][0] = (f32x4){0.f, 0.f, 0.f, 0.f};
            acc[m][1] = (f32x4){0.f, 0.f, 0.f, 0.f};
        }

        // ---- chunk top: prior chunk fully consumed ----
        __syncthreads();

        if (PRE) {
            ISSUE_W(0, 0); ISSUE_A(0, 0);
            ISSUE_W(1, 1); ISSUE_A(1, 1);
            WAITVM(3);                      // stage0's 3 landed; stage1 in flight
            BAR();
            int s0 = 0, s1 = 1, s2 = 2;
            for (int p = 0; p < NPH; ++p) {
                if (p + 2 < NPH) { ISSUE_W(s2, p + 2); ISSUE_A(s2, p + 2); SFENCE(); }
                STEP(s0);
                if (p + 2 < NPH)      { WAITVM(3); }   // p+1 landed; p+2 in flight
                else if (p + 1 < NPH) { WAITVM(0); }   // tail drain
                if (p + 1 < NPH) BAR();
                int tmp = s0; s0 = s1; s1 = s2; s2 = tmp;
            }
        } else {
            // ---- fallback (unused when workspace suffices): drain dbuf ----
            for (int p = 0; p < NPH; ++p) {
                float4 a0 = *(const float4*)(afsrc + p * KC);
                float4 a1 = *(const float4*)(afsrc + p * KC + 4);
                ISSUE_W(0, p);
                __syncthreads();            // readers of previous phase done
                *(short8*)(lds + AS(0) + t * 16) = pack8(a0, a1);
                WAITVM(0);
                __syncthreads();            // data visible
                STEP(0);
            }
        }

        // ---- epilogue: C layout col=lane&15, row=(lane>>4)*4+reg ----
        const int col0 = oc + wn * 32 + frow;
        #pragma unroll
        for (int m = 0; m < 8; ++m) {
            #pragma unroll
            for (int reg = 0; reg < 4; ++reg) {
                int r = wm * 128 + m * 16 + fks * 4 + reg;
                if (r < rows) {
                    int tok = perm[c0 + r];
                    float* orow = out + (size_t)tok * ODIM + col0;
                    orow[0]  = acc[m][0][reg];
                    orow[16] = acc[m][1][reg];
                }
            }
        }
    }
#undef ISSUE_W
#undef ISSUE_A
#undef STEP
}

extern "C" void kernel_launch(void* const* d_in, const int* in_sizes, int n_in,
                              void* d_out, int out_size, void* d_ws, size_t ws_size,
                              hipStream_t stream) {
    const float* inp    = (const float*)d_in[0];
    const int*   gate   = (const int*)d_in[1];
    const float* weight = (const float*)d_in[2];
    float*       out    = (float*)d_out;

    int* perm = (int*)d_ws;                          // 2048 ints
    int* offs = perm + NTOK;                         // 17 ints
    unsigned short* A2T2 = (unsigned short*)((char*)d_ws + 16384);
    const size_t need = 16384 + (size_t)NTOK * KDIM * 2 + 65536;
    const bool pre = (ws_size >= need);              // host-side, deterministic

    moe_sort<<<1, 256, 0, stream>>>(gate, perm, offs);
    if (pre) {
        dim3 cg(KDIM / 8, NTOK / 256);               // 128 x 8
        moe_cvt<<<cg, 256, 0, stream>>>(inp, perm, A2T2);
        moe_gemm<true><<<NBLK, 1024, 0, stream>>>(inp, A2T2, weight, perm, offs, out);
    } else {
        moe_gemm<false><<<NBLK, 1024, 0, stream>>>(inp, A2T2, weight, perm, offs, out);
    }
}

// Round 14
// 87.781 us; speedup vs baseline: 1.5551x; 1.0904x over previous
//
#include <hip/hip_runtime.h>
#include <hip/hip_bf16.h>

#define NEXP 16
#define KDIM 1024
#define ODIM 4096
#define NTOK 2048

#define BM   160                    // token rows per chunk (n_e ~ 128+-11)
#define BN   256                    // output cols per block (8 col-groups x 32)
#define KC   32                     // K per compute phase
#define KC2  64                     // K per W stage (256B/row contiguous)
#define NPH  (KDIM / KC)            // 32 phases
#define NBLK (NEXP * (ODIM / BN))   // 256 blocks = 1 per CU

// LDS: W 2 stages x [256 row][16 slot][16B] fp32 = 131072; A 3 stages x
// [4 oct][160 pos][16B] bf16 = 30720. Total 161792 <= 163840.
#define WS(s) ((s) * 65536)
#define AS(s) (131072 + (s) * 10240)
#define LDS_BYTES 161792

typedef __attribute__((ext_vector_type(8))) short short8;
typedef __attribute__((ext_vector_type(4))) float f32x4;

typedef __attribute__((address_space(3))) unsigned lds_uint;
typedef const __attribute__((address_space(1))) unsigned glob_uint;

__device__ __forceinline__ void gload16(const void* g, void* l) {
    __builtin_amdgcn_global_load_lds((glob_uint*)g, (lds_uint*)l, 16, 0, 0);
}

__device__ __forceinline__ unsigned short f2bf(float f) {
    __hip_bfloat16 h = __float2bfloat16(f);
    return __builtin_bit_cast(unsigned short, h);
}

__device__ __forceinline__ short8 pack8(float4 a, float4 b) {
    short8 r;
    r[0] = (short)f2bf(a.x); r[1] = (short)f2bf(a.y);
    r[2] = (short)f2bf(a.z); r[3] = (short)f2bf(a.w);
    r[4] = (short)f2bf(b.x); r[5] = (short)f2bf(b.y);
    r[6] = (short)f2bf(b.z); r[7] = (short)f2bf(b.w);
    return r;
}

__device__ __forceinline__ short8 pack8v(f32x4 a, f32x4 b) {
    short8 r;
    r[0] = (short)f2bf(a[0]); r[1] = (short)f2bf(a[1]);
    r[2] = (short)f2bf(a[2]); r[3] = (short)f2bf(a[3]);
    r[4] = (short)f2bf(b[0]); r[5] = (short)f2bf(b[1]);
    r[6] = (short)f2bf(b[2]); r[7] = (short)f2bf(b[3]);
    return r;
}

#define SFENCE() __builtin_amdgcn_sched_barrier(0)
#define WAITVM(N) do { SFENCE(); \
        asm volatile("s_waitcnt vmcnt(" #N ")" ::: "memory"); SFENCE(); } while (0)
#define BAR() do { SFENCE(); __builtin_amdgcn_s_barrier(); SFENCE(); } while (0)

// ---------------------------------------------------------------------------
// Kernel 1: deterministic counting sort of tokens by expert (unchanged).
// ---------------------------------------------------------------------------
__global__ __launch_bounds__(256) void moe_sort(const int* __restrict__ gate,
                                                int* __restrict__ perm,
                                                int* __restrict__ offs) {
    __shared__ int lgate[NTOK];
    __shared__ int hist[256][NEXP + 1];
    __shared__ int base[NEXP];
    const int t = threadIdx.x;
    for (int i = t; i < NTOK; i += 256) lgate[i] = gate[i];
    #pragma unroll
    for (int e = 0; e < NEXP; ++e) hist[t][e] = 0;
    __syncthreads();
    const int TPT = NTOK / 256;
    for (int j = 0; j < TPT; ++j) hist[t][lgate[t * TPT + j]]++;
    __syncthreads();
    if (t < NEXP) {
        int s = 0;
        for (int i = 0; i < 256; ++i) { int v = hist[i][t]; hist[i][t] = s; s += v; }
        base[t] = s;
    }
    __syncthreads();
    if (t == 0) {
        int s = 0;
        for (int e = 0; e < NEXP; ++e) { int v = base[e]; base[e] = s; offs[e] = s; s += v; }
        offs[NEXP] = s;
    }
    __syncthreads();
    #pragma unroll
    for (int e = 0; e < NEXP; ++e) hist[t][e] += base[e];
    for (int j = 0; j < TPT; ++j) {
        int tok = t * TPT + j;
        int e = lgate[tok];
        int pos = hist[t][e]++;
        perm[pos] = tok;
    }
}

// ---------------------------------------------------------------------------
// Kernel 1.5: gather+convert A to bf16, oct-major A2T2[oct][pos][8 bf16]
// (unchanged) -> GEMM A staging is a linear 16B-granule gload_lds copy.
// ---------------------------------------------------------------------------
__global__ __launch_bounds__(256) void moe_cvt(const float* __restrict__ inp,
                                               const int* __restrict__ perm,
                                               unsigned short* __restrict__ A2T2) {
    const int o   = blockIdx.x;                 // 0..127 k-octet
    const int pos = blockIdx.y * 256 + threadIdx.x;
    const int tok = perm[pos];
    const float4* s = (const float4*)(inp + (size_t)tok * KDIM + o * 8);
    float4 v0 = s[0], v1 = s[1];
    *(short8*)(A2T2 + ((size_t)o * NTOK + pos) * 8) = pack8(v0, v1);
}

// ---------------------------------------------------------------------------
// Kernel 2: grouped GEMM, KC2=64 W stages (256B contiguous per DRAM row
// visit). W: 2 stages x 64KB, issued once per phase-PAIR; source pre-swizzled
// slot^(row&15) (rule 21), frag reads conflict-free (R8/R12 family).
// A: 3 stages x 10KB (BM=160), issue p+2 each phase (waves 0-9 only).
// Counted vmcnt, WAVE-CLASS-SPECIFIC (R13 bugfix: waves 10-15 issue only W,
// so the astage counts would leave 1 W granule un-landed):
//   astage waves: even-end vmcnt(5) [retire A(p+1)], odd-end vmcnt(1)
//     [retire A(p+2)+W4, keep A(p+3)];
//   W-only waves: even-end none, odd-end vmcnt(0) [W pair j+1 landed].
// 1 block/CU, 16 waves (2 wm x 8 wn).
// ---------------------------------------------------------------------------
template <bool PRE>
__global__ __launch_bounds__(1024, 4) void moe_gemm(
    const float* __restrict__ inp,
    const unsigned short* __restrict__ A2T2,
    const float* __restrict__ weight,
    const int* __restrict__ perm,
    const int* __restrict__ offs,
    float* __restrict__ out)
{
    const int bid = blockIdx.x;
    const int v   = (bid & 7) * (NBLK / 8) + (bid >> 3); // 32 consec/XCD = 2 experts
    const int e   = v >> 4;                              // 16 oc-tiles per expert
    const int oc  = (v & 15) * BN;

    const int beg = offs[e], end = offs[e + 1];
    const int nall = end - beg;
    if (nall <= 0) return;

    __shared__ char lds[LDS_BYTES];

    const int t    = threadIdx.x;          // 0..1023
    const int lane = t & 63;
    const int w    = t >> 6;               // 0..15
    const int wm   = w >> 3;               // row half (80 rows)
    const int wn   = w & 7;                // col group (32 cols)
    const int frow = lane & 15;
    const int fks  = lane >> 4;            // 0..3 = k-octet within KC

    // ---- W staging: 4 granules per thread, g = t + q*1024;
    //      row = g>>4, slot = g&15, src slot = slot ^ (row&15) ----
    const float* bsrc[4];
    #pragma unroll
    for (int q = 0; q < 4; ++q) {
        int g = t + q * 1024;
        int row = g >> 4, slot = g & 15;
        bsrc[q] = weight + ((size_t)e * ODIM + oc + row) * KDIM
                  + (slot ^ (row & 15)) * 4;
    }
    // ---- A staging: waves 0-9 (t<640), granule t -> oct t/160, pos t%160 ----
    const bool astage = (t < 640);         // wave-uniform (wave 10 starts at 640)
    const int aoct = t / 160;
    const int apos = t - aoct * 160;

#define ISSUE_W(s, ks2) {                                                     \
        _Pragma("unroll")                                                     \
        for (int q = 0; q < 4; ++q)                                           \
            gload16(bsrc[q] + (ks2) * KC2, lds + WS(s) + (t + q * 1024) * 16);\
    }
#define ISSUE_A(s, p) {                                                       \
        if (astage)                                                           \
            gload16(asrcB + (size_t)(p) * (4 * NTOK * 8),                     \
                    lds + AS(s) + t * 16);                                    \
    }
#define STEP(sw, q, sa) {                                                     \
        const char* Wb = lds + WS(sw);                                        \
        const char* Ab = lds + AS(sa);                                        \
        int rB = wn * 32 + frow;                                              \
        const int x = rB & 15;                                                \
        f32x4 lo = *(const f32x4*)(Wb + (rB * 16 + (((q)*8 + 2*fks)     ^ x)) * 16); \
        f32x4 hi = *(const f32x4*)(Wb + (rB * 16 + (((q)*8 + 2*fks + 1) ^ x)) * 16); \
        short8 bf0 = pack8v(lo, hi);                                          \
        rB += 16;                                                             \
        lo = *(const f32x4*)(Wb + (rB * 16 + (((q)*8 + 2*fks)     ^ x)) * 16);\
        hi = *(const f32x4*)(Wb + (rB * 16 + (((q)*8 + 2*fks + 1) ^ x)) * 16);\
        short8 bf1 = pack8v(lo, hi);                                          \
        _Pragma("unroll")                                                     \
        for (int m = 0; m < 5; ++m) {                                         \
            if (m * 16 < mmax) {                                              \
                short8 af = *(const short8*)(Ab +                             \
                    (fks * BM + wm * 80 + m * 16 + frow) * 16);               \
                acc[m][0] = __builtin_amdgcn_mfma_f32_16x16x32_bf16(af, bf0, acc[m][0], 0, 0, 0); \
                acc[m][1] = __builtin_amdgcn_mfma_f32_16x16x32_bf16(af, bf1, acc[m][1], 0, 0, 0); \
            }                                                                 \
        }                                                                     \
    }

    for (int base = 0; base < nall; base += BM) {
        const int rows = (nall - base < BM) ? (nall - base) : BM;
        const int c0   = beg + base;
        const int mmax = rows - wm * 80;   // wave-uniform active m extent

        int rcl = apos; if (rcl > rows - 1) rcl = rows - 1;
        const unsigned short* asrcB =
            A2T2 + ((size_t)aoct * NTOK + (c0 + rcl)) * 8;

        f32x4 acc[5][2];
        #pragma unroll
        for (int m = 0; m < 5; ++m) {
            acc[m][0] = (f32x4){0.f, 0.f, 0.f, 0.f};
            acc[m][1] = (f32x4){0.f, 0.f, 0.f, 0.f};
        }

        // ---- chunk top: prior chunk fully consumed ----
        __syncthreads();

        if (PRE) {
            // prologue: A(0), A(1), W stage0 (ks2=0); drain; barrier
            ISSUE_A(0, 0);
            ISSUE_A(1, 1);
            ISSUE_W(0, 0);
            WAITVM(0);
            BAR();
            // pairs j=0..14 (phases 0..29); A-stage rotation sa = p%3
            int sa0 = 0, sa1 = 1, sa2 = 2;
            for (int j = 0; j < 15; ++j) {
                const int sw = j & 1;
                // even phase p=2j: issue A(p+2) [first], W(ks2=j+1); STEP
                ISSUE_A(sa2, 2 * j + 2);
                ISSUE_W(sw ^ 1, j + 1);
                SFENCE();
                STEP(sw, 0, sa0);
                if (astage) { WAITVM(5); }  // retire A(p+1); A(p+2)+W4 in flight
                BAR();
                { int tmp = sa0; sa0 = sa1; sa1 = sa2; sa2 = tmp; }
                // odd phase p=2j+1: issue A(p+2); STEP
                ISSUE_A(sa2, 2 * j + 3);
                SFENCE();
                STEP(sw, 1, sa0);
                if (astage) { WAITVM(1); }  // retire A(p+1)+W pair j+1; keep A(p+2)
                else        { WAITVM(0); }  // W-only waves: pair j+1 fully landed
                BAR();
                { int tmp = sa0; sa0 = sa1; sa1 = sa2; sa2 = tmp; }
            }
            // tail: phases 30, 31 on W stage 1
            STEP(1, 0, sa0);
            WAITVM(0);                   // A(31) landed (no-op for W-only waves)
            BAR();
            { int tmp = sa0; sa0 = sa1; sa1 = sa2; sa2 = tmp; }
            STEP(1, 1, sa0);
        } else {
            // ---- fallback (unused when workspace suffices): drain per phase ----
            const float* afsrc = inp + (size_t)perm[c0 + rcl] * KDIM + aoct * 8;
            for (int p = 0; p < NPH; ++p) {
                __syncthreads();         // readers of previous phase done
                if ((p & 1) == 0) ISSUE_W(0, p >> 1);
                if (astage) {
                    float4 a0 = *(const float4*)(afsrc + p * KC);
                    float4 a1 = *(const float4*)(afsrc + p * KC + 4);
                    *(short8*)(lds + AS(0) + t * 16) = pack8(a0, a1);
                }
                WAITVM(0);
                __syncthreads();         // data visible
                STEP(0, p & 1, 0);
            }
        }

        // ---- epilogue: C layout col=lane&15, row=(lane>>4)*4+reg ----
        const int col0 = oc + wn * 32 + frow;
        #pragma unroll
        for (int m = 0; m < 5; ++m) {
            #pragma unroll
            for (int reg = 0; reg < 4; ++reg) {
                int r = wm * 80 + m * 16 + fks * 4 + reg;
                if (r < rows) {
                    int tok = perm[c0 + r];
                    float* orow = out + (size_t)tok * ODIM + col0;
                    orow[0]  = acc[m][0][reg];
                    orow[16] = acc[m][1][reg];
                }
            }
        }
    }
#undef ISSUE_W
#undef ISSUE_A
#undef STEP
}

extern "C" void kernel_launch(void* const* d_in, const int* in_sizes, int n_in,
                              void* d_out, int out_size, void* d_ws, size_t ws_size,
                              hipStream_t stream) {
    const float* inp    = (const float*)d_in[0];
    const int*   gate   = (const int*)d_in[1];
    const float* weight = (const float*)d_in[2];
    float*       out    = (float*)d_out;

    int* perm = (int*)d_ws;                          // 2048 ints
    int* offs = perm + NTOK;                         // 17 ints
    unsigned short* A2T2 = (unsigned short*)((char*)d_ws + 16384);
    const size_t need = 16384 + (size_t)NTOK * KDIM * 2 + 65536;
    const bool pre = (ws_size >= need);              // host-side, deterministic

    moe_sort<<<1, 256, 0, stream>>>(gate, perm, offs);
    if (pre) {
        dim3 cg(KDIM / 8, NTOK / 256);               // 128 x 8
        moe_cvt<<<cg, 256, 0, stream>>>(inp, perm, A2T2);
        moe_gemm<true><<<NBLK, 1024, 0, stream>>>(inp, A2T2, weight, perm, offs, out);
    } else {
        moe_gemm<false><<<NBLK, 1024, 0, stream>>>(inp, A2T2, weight, perm, offs, out);
    }
}

// Round 15
// 86.372 us; speedup vs baseline: 1.5805x; 1.0163x over previous
//
#include <hip/hip_runtime.h>
#include <hip/hip_bf16.h>

#define NEXP 16
#define KDIM 1024
#define ODIM 4096
#define NTOK 2048

#define BM   160                    // token rows per chunk (n_e ~ 128+-11)
#define BN   256                    // output cols per block (8 col-groups x 32)
#define KC   32                     // K per phase
#define NPH  (KDIM / KC)            // 32 phases
#define NBLK (NEXP * (ODIM / BN))   // 256 blocks = 1 per CU

// LDS: W 3 stages x [256 row][8 slot][16B] fp32 = 98304; A 3 stages x
// [4 oct][160 pos][16B] bf16 = 30720. Total 129024 <= 163840.
#define WS(s) ((s) * 32768)
#define AS(s) (98304 + (s) * 10240)
#define LDS_BYTES 129024

typedef __attribute__((ext_vector_type(8))) short short8;
typedef __attribute__((ext_vector_type(4))) float f32x4;

typedef __attribute__((address_space(3))) unsigned lds_uint;
typedef const __attribute__((address_space(1))) unsigned glob_uint;

__device__ __forceinline__ void gload16(const void* g, void* l) {
    __builtin_amdgcn_global_load_lds((glob_uint*)g, (lds_uint*)l, 16, 0, 0);
}

__device__ __forceinline__ unsigned short f2bf(float f) {
    __hip_bfloat16 h = __float2bfloat16(f);
    return __builtin_bit_cast(unsigned short, h);
}

__device__ __forceinline__ short8 pack8(float4 a, float4 b) {
    short8 r;
    r[0] = (short)f2bf(a.x); r[1] = (short)f2bf(a.y);
    r[2] = (short)f2bf(a.z); r[3] = (short)f2bf(a.w);
    r[4] = (short)f2bf(b.x); r[5] = (short)f2bf(b.y);
    r[6] = (short)f2bf(b.z); r[7] = (short)f2bf(b.w);
    return r;
}

__device__ __forceinline__ short8 pack8v(f32x4 a, f32x4 b) {
    short8 r;
    r[0] = (short)f2bf(a[0]); r[1] = (short)f2bf(a[1]);
    r[2] = (short)f2bf(a[2]); r[3] = (short)f2bf(a[3]);
    r[4] = (short)f2bf(b[0]); r[5] = (short)f2bf(b[1]);
    r[6] = (short)f2bf(b[2]); r[7] = (short)f2bf(b[3]);
    return r;
}

#define SFENCE() __builtin_amdgcn_sched_barrier(0)
#define WAITVM(N) do { SFENCE(); \
        asm volatile("s_waitcnt vmcnt(" #N ")" ::: "memory"); SFENCE(); } while (0)
#define BAR() do { SFENCE(); __builtin_amdgcn_s_barrier(); SFENCE(); } while (0)

// ---------------------------------------------------------------------------
// Kernel 1: deterministic counting sort of tokens by expert (unchanged).
// ---------------------------------------------------------------------------
__global__ __launch_bounds__(256) void moe_sort(const int* __restrict__ gate,
                                                int* __restrict__ perm,
                                                int* __restrict__ offs) {
    __shared__ int lgate[NTOK];
    __shared__ int hist[256][NEXP + 1];
    __shared__ int base[NEXP];
    const int t = threadIdx.x;
    for (int i = t; i < NTOK; i += 256) lgate[i] = gate[i];
    #pragma unroll
    for (int e = 0; e < NEXP; ++e) hist[t][e] = 0;
    __syncthreads();
    const int TPT = NTOK / 256;
    for (int j = 0; j < TPT; ++j) hist[t][lgate[t * TPT + j]]++;
    __syncthreads();
    if (t < NEXP) {
        int s = 0;
        for (int i = 0; i < 256; ++i) { int v = hist[i][t]; hist[i][t] = s; s += v; }
        base[t] = s;
    }
    __syncthreads();
    if (t == 0) {
        int s = 0;
        for (int e = 0; e < NEXP; ++e) { int v = base[e]; base[e] = s; offs[e] = s; s += v; }
        offs[NEXP] = s;
    }
    __syncthreads();
    #pragma unroll
    for (int e = 0; e < NEXP; ++e) hist[t][e] += base[e];
    for (int j = 0; j < TPT; ++j) {
        int tok = t * TPT + j;
        int e = lgate[tok];
        int pos = hist[t][e]++;
        perm[pos] = tok;
    }
}

// ---------------------------------------------------------------------------
// Kernel 1.5: gather+convert A to bf16, oct-major A2T2[oct][pos][8 bf16]
// (unchanged) -> GEMM A staging is a linear 16B-granule gload_lds copy.
// ---------------------------------------------------------------------------
__global__ __launch_bounds__(256) void moe_cvt(const float* __restrict__ inp,
                                               const int* __restrict__ perm,
                                               unsigned short* __restrict__ A2T2) {
    const int o   = blockIdx.x;                 // 0..127 k-octet
    const int pos = blockIdx.y * 256 + threadIdx.x;
    const int tok = perm[pos];
    const float4* s = (const float4*)(inp + (size_t)tok * KDIM + o * 8);
    float4 v0 = s[0], v1 = s[1];
    *(short8*)(A2T2 + ((size_t)o * NTOK + pos) * 8) = pack8(v0, v1);
}

// ---------------------------------------------------------------------------
// Kernel 2: grouped GEMM, uniform 3-stage pipeline on BOTH streams.
// Rate analysis (R12 vs R14): delivery rate is insensitive to W run length
// but sensitive to issue smoothness. So: KC2 back to 32 (R12-verified
// swizzle), W and A both 3-stage; at the start of phase p each thread
// issues its stage-(p+2) loads (2 W granules; waves 0-9 also 1 A granule);
// STEP(p); class-counted vmcnt (3 astage / 2 W-only) retires stage p+1,
// keeps p+2 in flight; one barrier per phase. In-flight ~2 stages = 84 KB/CU,
// never drains until the tail. 42 KB/CU-phase staged. 1 block/CU, 16 waves.
// ---------------------------------------------------------------------------
template <bool PRE>
__global__ __launch_bounds__(1024, 4) void moe_gemm(
    const float* __restrict__ inp,
    const unsigned short* __restrict__ A2T2,
    const float* __restrict__ weight,
    const int* __restrict__ perm,
    const int* __restrict__ offs,
    float* __restrict__ out)
{
    const int bid = blockIdx.x;
    const int v   = (bid & 7) * (NBLK / 8) + (bid >> 3); // 32 consec/XCD = 2 experts
    const int e   = v >> 4;                              // 16 oc-tiles per expert
    const int oc  = (v & 15) * BN;

    const int beg = offs[e], end = offs[e + 1];
    const int nall = end - beg;
    if (nall <= 0) return;

    __shared__ char lds[LDS_BYTES];

    const int t    = threadIdx.x;          // 0..1023
    const int lane = t & 63;
    const int w    = t >> 6;               // 0..15
    const int wm   = w >> 3;               // row half (80 rows)
    const int wn   = w & 7;                // col group (32 cols)
    const int frow = lane & 15;
    const int fks  = lane >> 4;            // 0..3 = k-octet within KC

    // ---- W staging: 2 granules per thread, g = t + q*1024 (q=0,1);
    //      row = g>>3 (0..255), slot = g&7, src slot = slot ^ (row&7) ----
    const float* bsrc[2];
    #pragma unroll
    for (int q = 0; q < 2; ++q) {
        int g = t + q * 1024;
        int row = g >> 3, slot = g & 7;
        bsrc[q] = weight + ((size_t)e * ODIM + oc + row) * KDIM
                  + (slot ^ (row & 7)) * 4;
    }
    // ---- A staging: waves 0-9 (t<640), granule t -> oct t/160, pos t%160 ----
    const bool astage = (t < 640);         // wave-uniform (wave 10 starts at 640)
    const int aoct = t / 160;
    const int apos = t - aoct * 160;

#define ISSUE_W(s, p) {                                                       \
        gload16(bsrc[0] + (p) * KC, lds + WS(s) + t * 16);                    \
        gload16(bsrc[1] + (p) * KC, lds + WS(s) + 16384 + t * 16);            \
    }
#define ISSUE_A(s, p) {                                                       \
        if (astage)                                                           \
            gload16(asrcB + (size_t)(p) * (4 * NTOK * 8),                     \
                    lds + AS(s) + t * 16);                                    \
    }
#define STEP(s) {                                                             \
        const char* Wb = lds + WS(s);                                         \
        const char* Ab = lds + AS(s);                                         \
        int rB = wn * 32 + frow;                                              \
        const int x = rB & 7;                                                 \
        f32x4 lo = *(const f32x4*)(Wb + (rB * 8 + ((2 * fks)     ^ x)) * 16); \
        f32x4 hi = *(const f32x4*)(Wb + (rB * 8 + ((2 * fks + 1) ^ x)) * 16); \
        short8 bf0 = pack8v(lo, hi);                                          \
        rB += 16;                                                             \
        lo = *(const f32x4*)(Wb + (rB * 8 + ((2 * fks)     ^ x)) * 16);       \
        hi = *(const f32x4*)(Wb + (rB * 8 + ((2 * fks + 1) ^ x)) * 16);       \
        short8 bf1 = pack8v(lo, hi);                                          \
        _Pragma("unroll")                                                     \
        for (int m = 0; m < 5; ++m) {                                         \
            if (m * 16 < mmax) {                                              \
                short8 af = *(const short8*)(Ab +                             \
                    (fks * BM + wm * 80 + m * 16 + frow) * 16);               \
                acc[m][0] = __builtin_amdgcn_mfma_f32_16x16x32_bf16(af, bf0, acc[m][0], 0, 0, 0); \
                acc[m][1] = __builtin_amdgcn_mfma_f32_16x16x32_bf16(af, bf1, acc[m][1], 0, 0, 0); \
            }                                                                 \
        }                                                                     \
    }

    for (int base = 0; base < nall; base += BM) {
        const int rows = (nall - base < BM) ? (nall - base) : BM;
        const int c0   = beg + base;
        const int mmax = rows - wm * 80;   // wave-uniform active m extent

        int rcl = apos; if (rcl > rows - 1) rcl = rows - 1;
        const unsigned short* asrcB =
            A2T2 + ((size_t)aoct * NTOK + (c0 + rcl)) * 8;

        f32x4 acc[5][2];
        #pragma unroll
        for (int m = 0; m < 5; ++m) {
            acc[m][0] = (f32x4){0.f, 0.f, 0.f, 0.f};
            acc[m][1] = (f32x4){0.f, 0.f, 0.f, 0.f};
        }

        // ---- chunk top: prior chunk fully consumed (full drain, rare) ----
        __syncthreads();

        if (PRE) {
            // prologue: stages 0,1 issued; wait stage0 (keep stage1 in flight)
            ISSUE_W(0, 0); ISSUE_A(0, 0);
            ISSUE_W(1, 1); ISSUE_A(1, 1);
            if (astage) { WAITVM(3); } else { WAITVM(2); }
            BAR();
            for (int p = 0; p < NPH; ++p) {
                const int s0 = p % 3;
                const int s2 = (p + 2) % 3;
                if (p + 2 < NPH) { ISSUE_W(s2, p + 2); ISSUE_A(s2, p + 2); SFENCE(); }
                STEP(s0);
                if (p + 2 < NPH) {
                    // retire stage p+1; keep p+2's loads in flight
                    if (astage) { WAITVM(3); } else { WAITVM(2); }
                } else if (p + 1 < NPH) {
                    WAITVM(0);               // tail: stage p+1 fully landed
                }
                if (p + 1 < NPH) BAR();
            }
        } else {
            // ---- fallback (unused when workspace suffices): drain per phase ----
            const float* afsrc = inp + (size_t)perm[c0 + rcl] * KDIM + aoct * 8;
            for (int p = 0; p < NPH; ++p) {
                __syncthreads();         // readers of previous phase done
                ISSUE_W(0, p);
                if (astage) {
                    float4 a0 = *(const float4*)(afsrc + p * KC);
                    float4 a1 = *(const float4*)(afsrc + p * KC + 4);
                    *(short8*)(lds + AS(0) + t * 16) = pack8(a0, a1);
                }
                WAITVM(0);
                __syncthreads();         // data visible
                STEP(0);
            }
        }

        // ---- epilogue: C layout col=lane&15, row=(lane>>4)*4+reg ----
        const int col0 = oc + wn * 32 + frow;
        #pragma unroll
        for (int m = 0; m < 5; ++m) {
            #pragma unroll
            for (int reg = 0; reg < 4; ++reg) {
                int r = wm * 80 + m * 16 + fks * 4 + reg;
                if (r < rows) {
                    int tok = perm[c0 + r];
                    float* orow = out + (size_t)tok * ODIM + col0;
                    orow[0]  = acc[m][0][reg];
                    orow[16] = acc[m][1][reg];
                }
            }
        }
    }
#undef ISSUE_W
#undef ISSUE_A
#undef STEP
}

extern "C" void kernel_launch(void* const* d_in, const int* in_sizes, int n_in,
                              void* d_out, int out_size, void* d_ws, size_t ws_size,
                              hipStream_t stream) {
    const float* inp    = (const float*)d_in[0];
    const int*   gate   = (const int*)d_in[1];
    const float* weight = (const float*)d_in[2];
    float*       out    = (float*)d_out;

    int* perm = (int*)d_ws;                          // 2048 ints
    int* offs = perm + NTOK;                         // 17 ints
    unsigned short* A2T2 = (unsigned short*)((char*)d_ws + 16384);
    const size_t need = 16384 + (size_t)NTOK * KDIM * 2 + 65536;
    const bool pre = (ws_size >= need);              // host-side, deterministic

    moe_sort<<<1, 256, 0, stream>>>(gate, perm, offs);
    if (pre) {
        dim3 cg(KDIM / 8, NTOK / 256);               // 128 x 8
        moe_cvt<<<cg, 256, 0, stream>>>(inp, perm, A2T2);
        moe_gemm<true><<<NBLK, 1024, 0, stream>>>(inp, A2T2, weight, perm, offs, out);
    } else {
        moe_gemm<false><<<NBLK, 1024, 0, stream>>>(inp, A2T2, weight, perm, offs, out);
    }
}